// Round 5
// baseline (286.725 us; speedup 1.0000x reference)
//
#include <hip/hip_runtime.h>
#include <math.h>

// CRF log-likelihood, B=2048, T=80, L=128 — v13: dual-chain wave.
//
// Evidence from v11/v12: two co-resident waves fully serialize (v11 110us @
// 2 waves/SIMD == v12 108us @ 1 wave/SIMD x 2 rounds) because block waves
// are rhythm-identical and phase-lock on the same stall points. A solo wave
// is ~3.3k cy/step vs ~700 cy issue work -> huge idle shadow that TLP can't
// fill but in-wave ILP can. v8 (the 64us baseline) had this property (fwd &
// bwd interleaved per wave); v9-v12 lost it.
//
// v13: ONE wave runs BOTH directions for its 2 batch rows:
//   fwd: a_t = exp(x_t) o (E^T a_{t-1}), t = 1..39
//   bwd: v_t = exp(x_t) o (E   v_{t+1}), t = 78..40
// Two fully independent dependency chains fill each other's MFMA/exp/load
// shadows inside the wave. Both matrices live in AGPRs (256); budget:
// 256 AGPR + ~220 arch < 512 unified regs @ launch_bounds(64,1) ->
// 1 wave/SIMD, 1024 single-wave blocks, ONE round, zero LDS, zero barriers
// (combine a_39 . E . v_40 is in-wave: the wave holds both end states).
//
// Layout per chain (q = lane>>4 owns states [32q,32q+32), a = lane&15,
// batch row = a&1, 8x column replication):
//   D (tile mt, reg r) -> state 32q+4mt+r ; B (tile kk, elem j) -> state
//   32q+8kk+j  => next B-frag = pack of own D regs (no cross-lane).
// Renorm every 4 steps (per-row max via shfl_xor {2,4,8,16,32}, one-step
// delayed apply), distance-1.5 ping-pong emission prefetch.

#define CRF_B 2048
#define CRF_T 80
#define CRF_L 128

typedef __attribute__((ext_vector_type(8))) short bf16x8_t;
typedef __attribute__((ext_vector_type(4))) float f32x4_t;

__device__ __forceinline__ unsigned short bft(float f) {
    return (unsigned short)(__float_as_uint(f) >> 16);
}
// pack two f32 -> one dword of 2 bf16 (truncation), lo in bits 15:0
__device__ __forceinline__ int pack2(float lo, float hi) {
    return (int)__builtin_amdgcn_perm(__float_as_uint(hi), __float_as_uint(lo),
                                      0x07060302u);
}

#define MFMA16(A, B, C) __builtin_amdgcn_mfma_f32_16x16x32_bf16((A), (B), (C), 0, 0, 0)

__global__ __launch_bounds__(64, 1) void crf_v13_kernel(
    const float* __restrict__ x,           // [B,T,L]
    const float* __restrict__ trans,       // [L,L]
    const float* __restrict__ start_trans, // [L]
    const float* __restrict__ end_trans,   // [L]
    const int*   __restrict__ y,           // [B,T]
    float* __restrict__ out)               // [B]
{
    const int lane = threadIdx.x & 63;
    const int q    = lane >> 4;         // quad: owns states [32q, 32q+32)
    const int a    = lane & 15;         // MFMA n-column; batch row = a & 1
    const int row0 = blockIdx.x * 2;
    const int brow = row0 + (a & 1);

    // ---------------- numerators for rows row0, row0+1 (in-wave) ----------------
    float num0, num1;
    #pragma unroll
    for (int rr = 0; rr < 2; ++rr) {
        const int bb = row0 + rr;
        const int* yb = y + bb * CRF_T;
        const float* xbn = x + (size_t)bb * CRF_T * CRF_L;
        float p = 0.f;
        for (int t = lane; t < CRF_T; t += 64) {
            const int yt = yb[t];
            p += xbn[t * CRF_L + yt];
            p += (t + 1 < CRF_T) ? trans[yt * CRF_L + yb[t + 1]] : end_trans[yt];
            if (t == 0) p += start_trans[yt];
        }
        #pragma unroll
        for (int off = 1; off <= 32; off <<= 1) p += __shfl_xor(p, off);
        if (rr == 0) num0 = p; else num1 = p;
    }

    // ---------------- A-fragments: BOTH matrices, relabeled ----------------
    // out_state = 32*(a>>2) + 4*mt + (a&3), in_state = 32*q + 8*kk + j.
    // fwd AfF = E^T: E^T[out][in] = exp(trans[in][out])
    // bwd AfB = E  : E  [out][in] = exp(trans[out][in])
    bf16x8_t AfF[8][4], AfB[8][4];
    {
        const int out_lo = 32 * (a >> 2) + (a & 3);
        #pragma unroll
        for (int mt = 0; mt < 8; ++mt) {
            const int om = out_lo + 4 * mt;
            #pragma unroll
            for (int kk = 0; kk < 4; ++kk) {
                union { bf16x8_t v; unsigned short s[8]; } uF, uB;
                #pragma unroll
                for (int j = 0; j < 8; ++j) {
                    const int in_s = 32 * q + 8 * kk + j;
                    uF.s[j] = bft(__expf(trans[in_s * CRF_L + om]));
                    uB.s[j] = bft(__expf(trans[om * CRF_L + in_s]));
                }
                AfF[mt][kk] = uF.v;
                AfB[mt][kk] = uB.v;
            }
        }
    }

    const float* xr = x + (size_t)brow * CRF_T * CRF_L + 32 * q; // lane base

    // ---------------- init: a_0 and v_79 -> packed B-frags ----------------
    bf16x8_t BfF[4], BfB[4];
    {
        #pragma unroll
        for (int kk = 0; kk < 4; ++kk) {
            union { bf16x8_t v; int wd[4]; } uF, uB;
            #pragma unroll
            for (int h = 0; h < 2; ++h) {
                const int mt = 2 * kk + h;
                const f32x4_t sv  = *(const f32x4_t*)&start_trans[32 * q + 4 * mt];
                const f32x4_t ev  = *(const f32x4_t*)&end_trans[32 * q + 4 * mt];
                const f32x4_t x0  = *(const f32x4_t*)&xr[0 * CRF_L + 4 * mt];
                const f32x4_t x79 = *(const f32x4_t*)&xr[79 * CRF_L + 4 * mt];
                const float f0 = __expf(sv[0] + x0[0]), f1 = __expf(sv[1] + x0[1]);
                const float f2 = __expf(sv[2] + x0[2]), f3 = __expf(sv[3] + x0[3]);
                const float b0 = __expf(ev[0] + x79[0]), b1 = __expf(ev[1] + x79[1]);
                const float b2 = __expf(ev[2] + x79[2]), b3 = __expf(ev[3] + x79[3]);
                uF.wd[2 * h + 0] = pack2(f0, f1);
                uF.wd[2 * h + 1] = pack2(f2, f3);
                uB.wd[2 * h + 0] = pack2(b0, b1);
                uB.wd[2 * h + 1] = pack2(b2, b3);
            }
            BfF[kk] = uF.v;
            BfB[kk] = uB.v;
        }
    }

    // emission ping-pong buffers (both chains); preload F t=1, B t=78
    f32x4_t xF0[8], xF1[8], xB0[8], xB1[8];
    #pragma unroll
    for (int mt = 0; mt < 8; ++mt) {
        xF1[mt] = *(const f32x4_t*)&xr[1 * CRF_L + 4 * mt];
        xB1[mt] = *(const f32x4_t*)&xr[78 * CRF_L + 4 * mt];
    }

    float crF = 0.f, ivF = 1.f, MvF = 1.f;
    float crB = 0.f, ivB = 1.f, MvB = 1.f;
    int tF = 1;                         // current fwd t; bwd t = 79 - tF

    // One dual-chain step. CUR/NXT/MEASURE/APPLY/PF literal 0/1; all array
    // indices compile-time constant (no scratch).
#define CRF_STEP(CUR, NXT, MEASURE, APPLY, PF) do {                             \
        if (PF) {                                                               \
            const float* pF_ = xr + (size_t)(tF + 1) * CRF_L;                   \
            const float* pB_ = xr + (size_t)(78 - tF) * CRF_L;                  \
            _Pragma("unroll")                                                   \
            for (int mt = 0; mt < 8; ++mt) {                                    \
                xF##NXT[mt] = *(const f32x4_t*)&pF_[4 * mt];                    \
                xB##NXT[mt] = *(const f32x4_t*)&pB_[4 * mt];                    \
            }                                                                   \
        }                                                                       \
        if (APPLY) {                                                            \
            crF += __logf(MvF); ivF = __builtin_amdgcn_rcpf(MvF);               \
            crB += __logf(MvB); ivB = __builtin_amdgcn_rcpf(MvB);               \
        }                                                                       \
        float gF_ = 0.f, gB_ = 0.f;                                             \
        int bwF_[16], bwB_[16];                                                 \
        _Pragma("unroll")                                                       \
        for (int mt = 0; mt < 8; ++mt) {                                        \
            f32x4_t c_ = {0.f, 0.f, 0.f, 0.f};                                  \
            c_ = MFMA16(AfF[mt][0], BfF[0], c_);                                \
            c_ = MFMA16(AfF[mt][1], BfF[1], c_);                                \
            c_ = MFMA16(AfF[mt][2], BfF[2], c_);                                \
            c_ = MFMA16(AfF[mt][3], BfF[3], c_);                                \
            f32x4_t p_;                                                         \
            _Pragma("unroll")                                                   \
            for (int r = 0; r < 4; ++r) {                                       \
                float e_ = __expf(xF##CUR[mt][r]);                              \
                if (APPLY) e_ *= ivF;                                           \
                p_[r] = c_[r] * e_;                                             \
            }                                                                   \
            if (MEASURE)                                                        \
                gF_ = fmaxf(gF_, fmaxf(fmaxf(p_[0], p_[1]),                     \
                                       fmaxf(p_[2], p_[3])));                   \
            bwF_[2 * mt + 0] = pack2(p_[0], p_[1]);                             \
            bwF_[2 * mt + 1] = pack2(p_[2], p_[3]);                             \
        }                                                                       \
        _Pragma("unroll")                                                       \
        for (int mt = 0; mt < 8; ++mt) {                                        \
            f32x4_t c_ = {0.f, 0.f, 0.f, 0.f};                                  \
            c_ = MFMA16(AfB[mt][0], BfB[0], c_);                                \
            c_ = MFMA16(AfB[mt][1], BfB[1], c_);                                \
            c_ = MFMA16(AfB[mt][2], BfB[2], c_);                                \
            c_ = MFMA16(AfB[mt][3], BfB[3], c_);                                \
            f32x4_t p_;                                                         \
            _Pragma("unroll")                                                   \
            for (int r = 0; r < 4; ++r) {                                       \
                float e_ = __expf(xB##CUR[mt][r]);                              \
                if (APPLY) e_ *= ivB;                                           \
                p_[r] = c_[r] * e_;                                             \
            }                                                                   \
            if (MEASURE)                                                        \
                gB_ = fmaxf(gB_, fmaxf(fmaxf(p_[0], p_[1]),                     \
                                       fmaxf(p_[2], p_[3])));                   \
            bwB_[2 * mt + 0] = pack2(p_[0], p_[1]);                             \
            bwB_[2 * mt + 1] = pack2(p_[2], p_[3]);                             \
        }                                                                       \
        _Pragma("unroll")                                                       \
        for (int kk = 0; kk < 4; ++kk) {                                        \
            union { int wd[4]; bf16x8_t v; } uF_, uB_;                          \
            uF_.wd[0] = bwF_[4 * kk + 0]; uF_.wd[1] = bwF_[4 * kk + 1];         \
            uF_.wd[2] = bwF_[4 * kk + 2]; uF_.wd[3] = bwF_[4 * kk + 3];         \
            uB_.wd[0] = bwB_[4 * kk + 0]; uB_.wd[1] = bwB_[4 * kk + 1];         \
            uB_.wd[2] = bwB_[4 * kk + 2]; uB_.wd[3] = bwB_[4 * kk + 3];         \
            BfF[kk] = uF_.v;                                                    \
            BfB[kk] = uB_.v;                                                    \
        }                                                                       \
        if (MEASURE) {                                                          \
            gF_ = fmaxf(gF_, __shfl_xor(gF_, 2));                               \
            gF_ = fmaxf(gF_, __shfl_xor(gF_, 4));                               \
            gF_ = fmaxf(gF_, __shfl_xor(gF_, 8));                               \
            gF_ = fmaxf(gF_, __shfl_xor(gF_, 16));                              \
            gF_ = fmaxf(gF_, __shfl_xor(gF_, 32));                              \
            MvF = gF_;                                                          \
            gB_ = fmaxf(gB_, __shfl_xor(gB_, 2));                               \
            gB_ = fmaxf(gB_, __shfl_xor(gB_, 4));                               \
            gB_ = fmaxf(gB_, __shfl_xor(gB_, 8));                               \
            gB_ = fmaxf(gB_, __shfl_xor(gB_, 16));                              \
            gB_ = fmaxf(gB_, __shfl_xor(gB_, 32));                              \
            MvB = gB_;                                                          \
        }                                                                       \
        tF += 1;                                                                \
    } while (0)

    // ---------------- 39 dual steps: fwd t=1..39 / bwd t=78..40 ----------------
    // buffer parity = k & 1; measure at k = 4m+3, apply at k = 4m+4
    for (int k4 = 0; k4 < 9; ++k4) {
        CRF_STEP(1, 0, 0, 0, 1);   // k = 4m+1
        CRF_STEP(0, 1, 0, 0, 1);   // k = 4m+2
        CRF_STEP(1, 0, 1, 0, 1);   // k = 4m+3: measure
        CRF_STEP(0, 1, 0, 1, 1);   // k = 4m+4: apply
    }
    CRF_STEP(1, 0, 0, 0, 1);       // k = 37
    CRF_STEP(0, 1, 0, 0, 1);       // k = 38 (loads t=39 / t=40)
    CRF_STEP(1, 0, 0, 0, 0);       // k = 39 (no prefetch)
#undef CRF_STEP

    // ---------------- combine (in-wave): Z = a_39 . (E v_40) ----------------
    // BfB = v_40 packed; u = E v_40 via AfB as-A. BfF = a_39 packed.
    // D-state (mt,r) = 4mt+r (+32q); BfF[kk] word wi holds states 8kk+2wi(+h).
    // For (mt,r): kk = mt>>1, wi = 2*(mt&1) + (r>>1), half = r&1.
    float s = 0.f;
    #pragma unroll
    for (int mt = 0; mt < 8; ++mt) {
        f32x4_t c_ = {0.f, 0.f, 0.f, 0.f};
        c_ = MFMA16(AfB[mt][0], BfB[0], c_);
        c_ = MFMA16(AfB[mt][1], BfB[1], c_);
        c_ = MFMA16(AfB[mt][2], BfB[2], c_);
        c_ = MFMA16(AfB[mt][3], BfB[3], c_);
        union { bf16x8_t v; unsigned int wd[4]; } uv;
        uv.v = BfF[mt >> 1];
        #pragma unroll
        for (int r = 0; r < 4; ++r) {
            const unsigned int wdv = uv.wd[2 * (mt & 1) + (r >> 1)];
            const float av = __uint_as_float((r & 1) ? (wdv & 0xFFFF0000u)
                                                     : (wdv << 16));
            s += av * c_[r];
        }
    }
    // sum the 4 quads (states partitioned by q); bit0 (row) stays separate
    s += __shfl_xor(s, 16);
    s += __shfl_xor(s, 32);
    if (lane < 2)
        out[row0 + lane] = (lane ? num1 : num0) - (crF + crB + __logf(s));
}

extern "C" void kernel_launch(void* const* d_in, const int* in_sizes, int n_in,
                              void* d_out, int out_size, void* d_ws, size_t ws_size,
                              hipStream_t stream) {
    const float* x     = (const float*)d_in[0];
    const float* trans = (const float*)d_in[1];
    const float* st    = (const float*)d_in[2];
    const float* et    = (const float*)d_in[3];
    const int*   y     = (const int*)d_in[4];
    float* out = (float*)d_out;

    crf_v13_kernel<<<CRF_B / 2, 64, 0, stream>>>(x, trans, st, et, y, out);
}

// Round 7
// 174.618 us; speedup vs baseline: 1.6420x; 1.6420x over previous
//
#include <hip/hip_runtime.h>
#include <math.h>

// CRF log-likelihood, B=2048, T=80, L=128 — v14b: v9's wave-autonomous
// recurrence + async LDS emission ring. (v14 had a macro token-paste bug:
// x##CUR vs buffers named xb0/xb1 — fixed to xb##CUR; no other change.)
//
// Cross-version invariant (v8/v9/v11/v12): per-step time 3.3-6.8k cy vs
// ~300 cy issue work, in every structure. Diagnosis: per-step x loads are
// 64-128 scattered 16B requests whose latency is re-exposed every step;
// register ping-pong can only buy 1 step of slack per 32 VGPRs.
//
// v14 fix: 8-slot wave-private LDS ring for emissions.
//  - global_load_lds width-16 stages t+7 into the slot freed last step
//    (2 instrs/step, coalesced 1KB each — kills the scatter).
//  - counted s_waitcnt vmcnt(12) inline asm: 14 loads in flight across
//    steps; horizon = 7 steps. Exact count: ops for t are #(2t-1,2t);
//    at step k total issued = 14+2k, need t=k+1 done -> wait <=12.
//  - ds_read_b128 dist-1 into ping-pong regs; granule swizzle
//    g_phys=(g+2q+r)&7 -> 16 distinct addrs, exactly 2 per bank-group
//    (2-way = free). Staging source per-lane inverse-swizzled; LDS dest
//    linear (global_load_lds requirement).
//  - no barriers in the loop (wave-private regions); one syncthreads at
//    the fwd/bwd combine only.
// Structure else = v9: 4 rows/wave (4x col replication), fwd|bwd waves,
// 512 blocks x 2 waves = 1024 waves = 1 round @ 1 wave/SIMD, relabeled
// no-cross-lane chain (D state 32q+4mt+r, B state 32q+8kk+j), renorm
// every 4 steps (max over quads via xor 16/32, delayed apply).

#define CRF_B 2048
#define CRF_T 80
#define CRF_L 128

typedef __attribute__((ext_vector_type(8))) short bf16x8_t;
typedef __attribute__((ext_vector_type(4))) float f32x4_t;

__device__ __forceinline__ unsigned short bft(float f) {
    return (unsigned short)(__float_as_uint(f) >> 16);
}
// pack two f32 -> one dword of 2 bf16 (truncation), lo in bits 15:0
__device__ __forceinline__ int pack2(float lo, float hi) {
    return (int)__builtin_amdgcn_perm(__float_as_uint(hi), __float_as_uint(lo),
                                      0x07060302u);
}
__device__ __forceinline__ void stage16(const float* g, float* l) {
    __builtin_amdgcn_global_load_lds(
        (const __attribute__((address_space(1))) void*)g,
        (__attribute__((address_space(3))) void*)l, 16, 0, 0);
}
#define MFMA16(A, B, C) __builtin_amdgcn_mfma_f32_16x16x32_bf16((A), (B), (C), 0, 0, 0)
#define VMWAIT(N) asm volatile("s_waitcnt vmcnt(" #N ")" ::: "memory")

__global__ __launch_bounds__(128, 1) void crf_v14_kernel(
    const float* __restrict__ x,           // [B,T,L]
    const float* __restrict__ trans,       // [L,L]
    const float* __restrict__ start_trans, // [L]
    const float* __restrict__ end_trans,   // [L]
    const int*   __restrict__ y,           // [B,T]
    float* __restrict__ out)               // [B]
{
    const int tid  = threadIdx.x;
    const int w    = tid >> 6;          // 0 = forward wave, 1 = backward wave
    const int lane = tid & 63;
    const int q    = lane >> 4;         // quad: owns states [32q, 32q+32)
    const int a    = lane & 15;         // MFMA n-column; batch row = a & 3
    const int row0 = blockIdx.x * 4;
    const int brow = row0 + (a & 3);

    // emission ring: [wave][slot][row][state], linear (no pad; swizzle is
    // in the granule rotation). 32 KB.
    __shared__ __attribute__((aligned(16))) float stage_x[2][8][4][128];
    __shared__ __attribute__((aligned(16))) float u_lds[4][132];
    __shared__ float crunB_lds[4];
    __shared__ float numb[4];

    // ---------------- numerator: wave w -> rows 2w, 2w+1 ----------------
    #pragma unroll
    for (int rr = 0; rr < 2; ++rr) {
        const int bb = row0 + 2 * w + rr;
        const int* yb = y + bb * CRF_T;
        const float* xbn = x + (size_t)bb * CRF_T * CRF_L;
        float p = 0.f;
        for (int t = lane; t < CRF_T; t += 64) {
            const int yt = yb[t];
            p += xbn[t * CRF_L + yt];
            p += (t + 1 < CRF_T) ? trans[yt * CRF_L + yb[t + 1]] : end_trans[yt];
            if (t == 0) p += start_trans[yt];
        }
        #pragma unroll
        for (int off = 1; off <= 32; off <<= 1) p += __shfl_xor(p, off);
        if (lane == 0) numb[2 * w + rr] = p;
    }

    // ---------------- A-fragments: full exp(trans), relabeled ----------------
    // out_state = 32*(a>>2) + 4*mt + (a&3), in_state = 32*q + 8*kk + j.
    // fwd: Ê = exp(trans[in][out]);  bwd: Ê = exp(trans[out][in]).
    bf16x8_t Afr[8][4];
    {
        const int out_lo = 32 * (a >> 2) + (a & 3);
        const int in_lo  = 32 * q;
        const int so = w ? CRF_L : 1;   // stride of out_s in trans
        const int si = w ? 1 : CRF_L;   // stride of in_s  in trans
        #pragma unroll
        for (int mt = 0; mt < 8; ++mt) {
            const int ob = (out_lo + 4 * mt) * so;
            #pragma unroll
            for (int kk = 0; kk < 4; ++kk) {
                union { bf16x8_t v; unsigned short s[8]; } u;
                #pragma unroll
                for (int j = 0; j < 8; ++j) {
                    const int in_s = in_lo + 8 * kk + j;
                    u.s[j] = bft(__expf(trans[ob + in_s * si]));
                }
                Afr[mt][kk] = u.v;
            }
        }
    }

    const int t0    = w ? 79 : 0;
    const int tstep = w ? -1 : 1;
    const float* xr = x + (size_t)brow * CRF_T * CRF_L + 32 * q; // lane base

    // ---------------- init: a_0 (fwd) / v_79 (bwd) -> Bfr ----------------
    bf16x8_t Bfr[4];
    {
        const float* bias = w ? end_trans : start_trans;
        const float* xp = xr + (size_t)t0 * CRF_L;
        const float* bp = bias + 32 * q;
        #pragma unroll
        for (int kk = 0; kk < 4; ++kk) {
            union { bf16x8_t v; int wd[4]; } u;
            #pragma unroll
            for (int h = 0; h < 2; ++h) {   // two 4-state groups per kk
                const int mt = 2 * kk + h;
                const f32x4_t bv = *(const f32x4_t*)&bp[4 * mt];
                const f32x4_t xv = *(const f32x4_t*)&xp[4 * mt];
                float p0 = __expf(bv[0] + xv[0]);
                float p1 = __expf(bv[1] + xv[1]);
                float p2 = __expf(bv[2] + xv[2]);
                float p3 = __expf(bv[3] + xv[3]);
                u.wd[2 * h + 0] = pack2(p0, p1);
                u.wd[2 * h + 1] = pack2(p2, p3);
            }
            Bfr[kk] = u.v;
        }
    }

    // ---------------- staging lane sources (inverse swizzle) ----------------
    // instr i covers LDS bytes [i*1024, i*1024+1024): linear offset o =
    // i*1024 + lane*16 -> row r = o>>9, quad q' = (o>>7)&3, granule
    // g_phys = (o>>4)&7. Stored there: states q'*32 + g_log*4 .. +3 of
    // row (row0+r), with g_log = (g_phys - 2q' - r) & 7.
    const float* sBase0;
    const float* sBase1;
    {
        const int r0_ = lane >> 5;
        const int r1_ = 2 + (lane >> 5);
        const int qp_ = (lane >> 3) & 3;
        const int gp_ = lane & 7;
        const int gl0 = (gp_ - 2 * qp_ - r0_) & 7;
        const int gl1 = (gp_ - 2 * qp_ - r1_) & 7;
        sBase0 = x + (size_t)(row0 + r0_) * CRF_T * CRF_L + qp_ * 32 + gl0 * 4;
        sBase1 = x + (size_t)(row0 + r1_) * CRF_T * CRF_L + qp_ * 32 + gl1 * 4;
    }
    // read-side: lane (q, a) reads states 32q+4mt..+3 of row (a&3) at
    // floats r*128 + q*32 + ((mt + 2q + r)&7)*4
    const int rdBase = (a & 3) * 128 + q * 32;
    const int rotc   = 2 * q + (a & 3);

    // clean vmcnt counter, then stage slots 1..7 (t0 +/- 1..7): 14 ops
    VMWAIT(0);
    for (int si = 1; si <= 7; ++si) {
        const int ts_ = t0 + si * tstep;
        float* lb_ = &stage_x[w][si][0][0];
        stage16(sBase0 + (size_t)ts_ * CRF_L, lb_);
        stage16(sBase1 + (size_t)ts_ * CRF_L, lb_ + 256);
    }
    VMWAIT(12);                         // t0+/-1 (ops #1,#2) complete

    // emission ping-pong; xb1 <- slot 1 (t = t0 +/- 1)
    f32x4_t xb0[8], xb1[8];
    {
        const float* rb_ = &stage_x[w][1][0][0];
        #pragma unroll
        for (int mt = 0; mt < 8; ++mt)
            xb1[mt] = *(const f32x4_t*)&rb_[rdBase + (((mt + rotc) & 7) << 2)];
    }

    float crun = 0.f, inv = 1.f, Mv = 1.f;
    int kcur = 1;

    // One recurrence step (t = t0 + kcur*tstep). CUR/NXT/MEASURE/APPLY/
    // STAGE/RDNEXT are literal 0/1, VM a literal count; all array indices
    // compile-time constant (no scratch).
#define CRF_STEP(CUR, NXT, MEASURE, APPLY, STAGE, RDNEXT, VM) do {              \
        if (STAGE) {                                                            \
            const int ts_ = t0 + (kcur + 7) * tstep;                            \
            float* lb_ = &stage_x[w][(kcur + 7) & 7][0][0];                     \
            stage16(sBase0 + (size_t)ts_ * CRF_L, lb_);                         \
            stage16(sBase1 + (size_t)ts_ * CRF_L, lb_ + 256);                   \
        }                                                                       \
        if (RDNEXT) {                                                           \
            VMWAIT(VM);                                                         \
            const float* rb_ = &stage_x[w][(kcur + 1) & 7][0][0];               \
            _Pragma("unroll")                                                   \
            for (int mt = 0; mt < 8; ++mt)                                      \
                xb##NXT[mt] = *(const f32x4_t*)                                 \
                    &rb_[rdBase + (((mt + rotc) & 7) << 2)];                    \
        }                                                                       \
        if (APPLY) { crun += __logf(Mv); inv = __builtin_amdgcn_rcpf(Mv); }     \
        float e_[8][4];                                                         \
        _Pragma("unroll")                                                       \
        for (int mt = 0; mt < 8; ++mt)                                          \
            _Pragma("unroll")                                                   \
            for (int r = 0; r < 4; ++r) {                                       \
                float v_ = __expf(xb##CUR[mt][r]);                              \
                if (APPLY) v_ *= inv;                                           \
                e_[mt][r] = v_;                                                 \
            }                                                                   \
        float g_ = 0.f;                                                         \
        int bw_[16];                                                            \
        _Pragma("unroll")                                                       \
        for (int mt = 0; mt < 8; ++mt) {                                        \
            f32x4_t c_ = {0.f, 0.f, 0.f, 0.f};                                  \
            c_ = MFMA16(Afr[mt][0], Bfr[0], c_);                                \
            c_ = MFMA16(Afr[mt][1], Bfr[1], c_);                                \
            c_ = MFMA16(Afr[mt][2], Bfr[2], c_);                                \
            c_ = MFMA16(Afr[mt][3], Bfr[3], c_);                                \
            f32x4_t p_;                                                         \
            _Pragma("unroll")                                                   \
            for (int r = 0; r < 4; ++r) p_[r] = c_[r] * e_[mt][r];              \
            if (MEASURE)                                                        \
                g_ = fmaxf(g_, fmaxf(fmaxf(p_[0], p_[1]),                       \
                                     fmaxf(p_[2], p_[3])));                     \
            bw_[2 * mt + 0] = pack2(p_[0], p_[1]);                              \
            bw_[2 * mt + 1] = pack2(p_[2], p_[3]);                              \
        }                                                                       \
        _Pragma("unroll")                                                       \
        for (int kk = 0; kk < 4; ++kk) {                                        \
            union { int wd[4]; bf16x8_t v; } u_;                                \
            u_.wd[0] = bw_[4 * kk + 0];                                         \
            u_.wd[1] = bw_[4 * kk + 1];                                         \
            u_.wd[2] = bw_[4 * kk + 2];                                         \
            u_.wd[3] = bw_[4 * kk + 3];                                         \
            Bfr[kk] = u_.v;                                                     \
        }                                                                       \
        if (MEASURE) {                                                          \
            g_ = fmaxf(g_, __shfl_xor(g_, 16));                                 \
            g_ = fmaxf(g_, __shfl_xor(g_, 32));                                 \
            Mv = g_;                                                            \
        }                                                                       \
        kcur += 1;                                                              \
    } while (0)

    // ---------------- 39 steps: fwd t=1..39, bwd t=78..40 ----------------
    // k = 1..32: stage t+7, vmcnt(12). k = 33..39: drain with exact counts.
    // cadence: measure at k = 4m+3 (3..35), apply at k = 4m+4 (4..36).
    for (int k4 = 0; k4 < 8; ++k4) {
        CRF_STEP(1, 0, 0, 0, 1, 1, 12);   // k = 4m+1
        CRF_STEP(0, 1, 0, 0, 1, 1, 12);   // k = 4m+2
        CRF_STEP(1, 0, 1, 0, 1, 1, 12);   // k = 4m+3: measure
        CRF_STEP(0, 1, 0, 1, 1, 1, 12);   // k = 4m+4: apply
    }
    CRF_STEP(1, 0, 0, 0, 0, 1, 10);       // k = 33
    CRF_STEP(0, 1, 0, 0, 0, 1, 8);        // k = 34
    CRF_STEP(1, 0, 1, 0, 0, 1, 6);        // k = 35: measure
    CRF_STEP(0, 1, 0, 1, 0, 1, 4);        // k = 36: apply
    CRF_STEP(1, 0, 0, 0, 0, 1, 2);        // k = 37
    CRF_STEP(0, 1, 0, 0, 0, 1, 0);        // k = 38
    CRF_STEP(1, 0, 0, 0, 0, 0, 0);        // k = 39 (no next read)
#undef CRF_STEP

    // ---------------- combine: Z = a_39 . (E v_40) ----------------
    // Bfr = a_39 (fwd) / v_40 (bwd), bf16-packed.
    if (w == 1) {
        #pragma unroll
        for (int mt = 0; mt < 8; ++mt) {
            f32x4_t c_ = {0.f, 0.f, 0.f, 0.f};
            c_ = MFMA16(Afr[mt][0], Bfr[0], c_);
            c_ = MFMA16(Afr[mt][1], Bfr[1], c_);
            c_ = MFMA16(Afr[mt][2], Bfr[2], c_);
            c_ = MFMA16(Afr[mt][3], Bfr[3], c_);
            if (a < 4)      // replica-0 lanes (= rows 0..3) write u
                *(f32x4_t*)&u_lds[a][32 * q + 4 * mt] = c_;
        }
        if (a < 4 && q == 0) crunB_lds[a] = crun;
    }
    __syncthreads();
    if (w == 0) {
        // a_39 from the bf16 pack; u from LDS. Bfr[kk] word wi half h ->
        // state 32q + 8kk + 2wi + h.
        float s = 0.f;
        #pragma unroll
        for (int kk = 0; kk < 4; ++kk) {
            union { bf16x8_t v; unsigned int wd[4]; } u_;
            u_.v = Bfr[kk];
            const f32x4_t uv0 = *(const f32x4_t*)&u_lds[a & 3][32 * q + 8 * kk];
            const f32x4_t uv1 = *(const f32x4_t*)&u_lds[a & 3][32 * q + 8 * kk + 4];
            #pragma unroll
            for (int wi = 0; wi < 4; ++wi) {
                const float vlo = __uint_as_float(u_.wd[wi] << 16);
                const float vhi = __uint_as_float(u_.wd[wi] & 0xFFFF0000u);
                const float ulo = (wi < 2) ? uv0[2 * wi]     : uv1[2 * wi - 4];
                const float uhi = (wi < 2) ? uv0[2 * wi + 1] : uv1[2 * wi - 3];
                s += vlo * ulo + vhi * uhi;
            }
        }
        // sum over quads: the 4 q-groups partition the 128 states
        s += __shfl_xor(s, 16);
        s += __shfl_xor(s, 32);
        if (a < 4 && q == 0)
            out[row0 + a] = numb[a] - (crun + crunB_lds[a] + __logf(s));
    }
}

extern "C" void kernel_launch(void* const* d_in, const int* in_sizes, int n_in,
                              void* d_out, int out_size, void* d_ws, size_t ws_size,
                              hipStream_t stream) {
    const float* x     = (const float*)d_in[0];
    const float* trans = (const float*)d_in[1];
    const float* st    = (const float*)d_in[2];
    const float* et    = (const float*)d_in[3];
    const int*   y     = (const int*)d_in[4];
    float* out = (float*)d_out;

    crf_v14_kernel<<<CRF_B / 4, 128, 0, stream>>>(x, trans, st, et, y, out);
}